// Round 6
// baseline (229.454 us; speedup 1.0000x reference)
//
#include <hip/hip_runtime.h>
#include <math.h>

#define NN 50000
#define NE 800000
#define NG 64

// ---------------- ws layout (float offsets) ----------------
#define WS_C     0                       // 8 floats: [h*4 + {att.Wl, att.Wr, att.We, att.B}]
#define WS_ACC   16                      // 4*NN floats: {den0,den1,t10,t11} per node (float4)
#define WS_BNSUM (WS_ACC + 4*NN)         // 128
#define WS_BNSQ  (WS_BNSUM + 128)        // 128
#define WS_HEAD  (WS_BNSQ + 128)         // 4*NN u32 chain heads (0xFFFFFFFF = end)
#define WS_PREV  (WS_HEAD + 4*NN)        // NE u32 next-pointers
#define WS_STAGE (WS_PREV + NE)          // NE float4 = {e0, e1, e0*xs, e1*xs}
#define WS_END   (WS_STAGE + 4*NE)
#define WS_NEED_BYTES ((size_t)WS_END * 4 + 256)

#define LEND 0xFFFFFFFFu

static_assert(((WS_STAGE * 4) % 16) == 0, "stage 16B alignment");
static_assert(NE % 4 == 0, "edge unroll");

// ---------------- k0: init + attention-dot constants ----------------
extern "C" __global__ __launch_bounds__(256)
void k0_init(float* __restrict__ ws,
             const float* __restrict__ att, const float* __restrict__ Wl,
             const float* __restrict__ Wr, const float* __restrict__ We,
             const float* __restrict__ bl, const float* __restrict__ br,
             float* __restrict__ out, int dense)
{
  int tid = blockIdx.x * 256 + threadIdx.x;
  int nt = gridDim.x * 256;
  if (dense) {
    unsigned* head = (unsigned*)(ws + WS_HEAD);
    for (int i = tid; i < 4 * NN; i += nt) head[i] = LEND;
  } else {
    for (int i = tid; i < 4 * NN; i += nt) ws[WS_ACC + i] = 0.f;  // atomic fallback needs zeros
  }
  for (int i = tid; i < 256; i += nt) ws[WS_BNSUM + i] = 0.f;
  for (int i = tid; i < NG * 128; i += nt) out[i] = 0.f;
  if (blockIdx.x == 0) {
    __shared__ float red[4][256];
    int t = threadIdx.x;                    // t = h*128 + d
    float a = att[t];
    red[0][t] = a * Wl[t];
    red[1][t] = a * Wr[t];
    red[2][t] = a * We[t];
    red[3][t] = a * (bl[t] + br[t]);
    __syncthreads();
    if (t < 8) {
      int k = t >> 1, h = t & 1;
      float s = 0.f;
      for (int d = 0; d < 128; ++d) s += red[k][h * 128 + d];
      ws[WS_C + h * 4 + k] = s;
    }
  }
}

// ---------------- shared score machinery ----------------
// score_h = 0.6*(C·[xs,xd,ae,1]) + 0.4*Σ_d att_d*|Wl_d*xs + Wr_d*xd + We_d*ae + B_d|
#define STEP(wl_, wr_, we_, bb_, at_, xs_, xd_, ae_, acc_)                 \
  { float tt = fmaf(we_, ae_, bb_); tt = fmaf(wr_, xd_, tt);               \
    tt = fmaf(wl_, xs_, tt); acc_ = fmaf(fabsf(tt), at_, acc_); }

#define STEP4(c, q0, q1, q2, q3)                                           \
  STEP(wl.c, wr.c, we.c, bb.c, at.c, xs0, xd0, ae0, q0)                    \
  STEP(wl.c, wr.c, we.c, bb.c, at.c, xs1, xd1, ae1, q1)                    \
  STEP(wl.c, wr.c, we.c, bb.c, at.c, xs2, xd2, ae2, q2)                    \
  STEP(wl.c, wr.c, we.c, bb.c, at.c, xs3, xd3, ae3, q3)

// Loads edges, x, eattr; runs the abs-dot loop; leaves a00..a13 + c0/c1 live.
#define SCORE_CORE                                                         \
  int4 s4 = *(const int4*)&ei[base];                                       \
  int4 dd4 = *(const int4*)&ei[NE + base];                                 \
  float4 ae4 = *(const float4*)&eattr[base];                               \
  float xs0 = x[s4.x], xs1 = x[s4.y], xs2 = x[s4.z], xs3 = x[s4.w];        \
  float xd0 = x[dd4.x], xd1 = x[dd4.y], xd2 = x[dd4.z], xd3 = x[dd4.w];    \
  float ae0 = ae4.x, ae1 = ae4.y, ae2 = ae4.z, ae3 = ae4.w;

#define SCORE_LOOPS                                                        \
  float a00 = 0.f, a01 = 0.f, a02 = 0.f, a03 = 0.f;                        \
  float a10 = 0.f, a11 = 0.f, a12 = 0.f, a13 = 0.f;                        \
  _Pragma("unroll 2")                                                      \
  for (int j = 0; j < 128; j += 4) {                                       \
    float4 wl = *(const float4*)&sWl[j];                                   \
    float4 wr = *(const float4*)&sWr[j];                                   \
    float4 we = *(const float4*)&sWe[j];                                   \
    float4 bb = *(const float4*)&sB[j];                                    \
    float4 at = *(const float4*)&sAt[j];                                   \
    STEP4(x, a00, a01, a02, a03)                                           \
    STEP4(y, a00, a01, a02, a03)                                           \
    STEP4(z, a00, a01, a02, a03)                                           \
    STEP4(w, a00, a01, a02, a03)                                           \
  }                                                                        \
  _Pragma("unroll 2")                                                      \
  for (int j = 128; j < 256; j += 4) {                                     \
    float4 wl = *(const float4*)&sWl[j];                                   \
    float4 wr = *(const float4*)&sWr[j];                                   \
    float4 we = *(const float4*)&sWe[j];                                   \
    float4 bb = *(const float4*)&sB[j];                                    \
    float4 at = *(const float4*)&sAt[j];                                   \
    STEP4(x, a10, a11, a12, a13)                                           \
    STEP4(y, a10, a11, a12, a13)                                           \
    STEP4(z, a10, a11, a12, a13)                                           \
    STEP4(w, a10, a11, a12, a13)                                           \
  }                                                                        \
  float4 c0 = *(const float4*)&ws[WS_C];                                   \
  float4 c1 = *(const float4*)&ws[WS_C + 4];

#define SMEM_WEIGHTS                                                       \
  __shared__ __align__(16) float sWl[256], sWr[256], sWe[256], sB[256], sAt[256]; \
  { int t = threadIdx.x;                                                   \
    sWl[t] = Wl[t]; sWr[t] = Wr[t]; sWe[t] = We[t];                        \
    sB[t] = bl[t] + br[t]; sAt[t] = att[t]; }                              \
  __syncthreads();

#define SCORES(xs_, xd_, ae_, accA, accB, out0, out1)                      \
  { float lin0 = fmaf(c0.x, xs_, fmaf(c0.y, xd_, fmaf(c0.z, ae_, c0.w))); \
    out0 = fmaf(0.4f, accA, 0.6f * lin0);                                  \
    float lin1 = fmaf(c1.x, xs_, fmaf(c1.y, xd_, fmaf(c1.z, ae_, c1.w))); \
    out1 = fmaf(0.4f, accB, 0.6f * lin1); }

// ---------------- ke: fused score+exp, 4-chain linked-list staging ----------------
// atomicExch issued BEFORE the score loop (latency hidden by ~1024 FMAs);
// payload store independent of exch; prev stored separately (coalesced 4B).
extern "C" __global__ __launch_bounds__(256)
void ke_edge(const int* __restrict__ ei, const float* __restrict__ x,
             const float* __restrict__ eattr,
             const float* __restrict__ Wl, const float* __restrict__ Wr,
             const float* __restrict__ We, const float* __restrict__ bl,
             const float* __restrict__ br, const float* __restrict__ att,
             float* __restrict__ ws)
{
  SMEM_WEIGHTS
  int base = (blockIdx.x * 256 + threadIdx.x) * 4;
  if (base >= NE) return;
  SCORE_CORE
  unsigned* head = (unsigned*)(ws + WS_HEAD);
  // issue the 4 random exchanges NOW; results consumed only at the end
  unsigned pv0 = atomicExch(&head[4 * dd4.x + 0], (unsigned)(base + 0));
  unsigned pv1 = atomicExch(&head[4 * dd4.y + 1], (unsigned)(base + 1));
  unsigned pv2 = atomicExch(&head[4 * dd4.z + 2], (unsigned)(base + 2));
  unsigned pv3 = atomicExch(&head[4 * dd4.w + 3], (unsigned)(base + 3));
  SCORE_LOOPS
  float4* stage = (float4*)(ws + WS_STAGE);
  unsigned* prev = (unsigned*)(ws + WS_PREV);
  float s0, s1;
  float4 pay0, pay1, pay2, pay3;
#define PAY(xs_, xd_, ae_, accA, accB, pp)                                 \
  { SCORES(xs_, xd_, ae_, accA, accB, s0, s1)                              \
    float e0 = __expf(s0), e1 = __expf(s1);                                \
    pp = make_float4(e0, e1, e0 * xs_, e1 * xs_); }
  PAY(xs0, xd0, ae0, a00, a10, pay0)
  PAY(xs1, xd1, ae1, a01, a11, pay1)
  PAY(xs2, xd2, ae2, a02, a12, pay2)
  PAY(xs3, xd3, ae3, a03, a13, pay3)
#undef PAY
  stage[base + 0] = pay0;
  stage[base + 1] = pay1;
  stage[base + 2] = pay2;
  stage[base + 3] = pay3;
  *(uint4*)&prev[base] = make_uint4(pv0, pv1, pv2, pv3);
}

// ---------------- kf: per-node 4-chain walk, 4-way ILP (0 atomics) ----------------
extern "C" __global__ __launch_bounds__(256)
void kf_gather(float* __restrict__ ws)
{
  int n = blockIdx.x * 256 + threadIdx.x;
  if (n >= NN) return;
  const unsigned* head = (const unsigned*)(ws + WS_HEAD);
  const unsigned* prev = (const unsigned*)(ws + WS_PREV);
  const float4* stage = (const float4*)(ws + WS_STAGE);
  uint4 p = *(const uint4*)&head[4 * n];
  float4 A0 = make_float4(0.f, 0.f, 0.f, 0.f);
  float4 A1 = A0, A2 = A0, A3 = A0;
  while ((p.x & p.y & p.z & p.w) != LEND) {
#define HOP(pc, Ac)                                                        \
    if (pc != LEND) {                                                      \
      float4 q = stage[pc];                                                \
      unsigned np = prev[pc];                                              \
      Ac.x += q.x; Ac.y += q.y; Ac.z += q.z; Ac.w += q.w;                  \
      pc = np;                                                             \
    }
    HOP(p.x, A0) HOP(p.y, A1) HOP(p.z, A2) HOP(p.w, A3)
#undef HOP
  }
  // drain any chains still active (loop exits only when ALL are done, so
  // the while above already drains everything; this is just the sum)
  float4 r;
  r.x = (A0.x + A1.x) + (A2.x + A3.x);
  r.y = (A0.y + A1.y) + (A2.y + A3.y);
  r.z = (A0.z + A1.z) + (A2.z + A3.z);
  r.w = (A0.w + A1.w) + (A2.w + A3.w);
  *(float4*)&ws[WS_ACC + 4 * n] = r;
}

// ---------------- fallback: fused score + exp + 4 atomics/edge (small ws) ----------------
extern "C" __global__ __launch_bounds__(256)
void k12f(const int* __restrict__ ei, const float* __restrict__ x,
          const float* __restrict__ eattr,
          const float* __restrict__ Wl, const float* __restrict__ Wr,
          const float* __restrict__ We, const float* __restrict__ bl,
          const float* __restrict__ br, const float* __restrict__ att,
          float* __restrict__ ws)
{
  SMEM_WEIGHTS
  int base = (blockIdx.x * 256 + threadIdx.x) * 4;
  if (base >= NE) return;
  SCORE_CORE
  SCORE_LOOPS
  float* acc = ws + WS_ACC;
  float s0, s1;
#define EPI2(xs_, xd_, ae_, accA, accB, dsti)                              \
  { SCORES(xs_, xd_, ae_, accA, accB, s0, s1)                              \
    float e0 = __expf(s0), e1 = __expf(s1);                                \
    float* a = &acc[4 * dsti];                                             \
    atomicAdd(a + 0, e0); atomicAdd(a + 1, e1);                            \
    atomicAdd(a + 2, e0 * xs_); atomicAdd(a + 3, e1 * xs_); }
  EPI2(xs0, xd0, ae0, a00, a10, dd4.x)
  EPI2(xs1, xd1, ae1, a01, a11, dd4.y)
  EPI2(xs2, xd2, ae2, a02, a12, dd4.z)
  EPI2(xs3, xd3, ae3, a03, a13, dd4.w)
#undef EPI2
}

// ---------------- node output from the 4 per-node scalars ----------------
__device__ __forceinline__ float node_out4(float4 a, float wl0, float wl1,
                                           float b0, float b1, float bs)
{
  float r0 = 1.f / (a.x + 1e-16f);
  float r1 = 1.f / (a.y + 1e-16f);
  return 0.5f * (fmaf(wl0, a.z * r0, b0 * (a.x * r0)) +
                 fmaf(wl1, a.w * r1, b1 * (a.y * r1))) + bs;
}

// ---------------- k3: BN statistics ----------------
extern "C" __global__ __launch_bounds__(256)
void k3_stats(const float* __restrict__ Wl, const float* __restrict__ bl,
              const float* __restrict__ bias, float* __restrict__ ws)
{
  int d = threadIdx.x & 127;
  int row = threadIdx.x >> 7;
  float wl0 = Wl[d], wl1 = Wl[128 + d];
  float b0 = bl[d], b1 = bl[128 + d];
  float bs = bias[d];
  float sum = 0.f, sq = 0.f;
  for (int n = blockIdx.x * 2 + row; n < NN; n += gridDim.x * 2) {
    float4 a = *(const float4*)&ws[WS_ACC + 4 * n];
    float o = node_out4(a, wl0, wl1, b0, b1, bs);
    sum += o;
    sq = fmaf(o, o, sq);
  }
  __shared__ float l1[256], l2[256];
  l1[threadIdx.x] = sum; l2[threadIdx.x] = sq;
  __syncthreads();
  if (row == 0) {
    atomicAdd(&ws[WS_BNSUM + d], l1[d] + l1[128 + d]);
    atomicAdd(&ws[WS_BNSQ + d], l2[d] + l2[128 + d]);
  }
}

// ---------------- k4: BN apply + leaky_relu + graph pooling ----------------
extern "C" __global__ __launch_bounds__(256)
void k4_pool(const int* __restrict__ batch,
             const float* __restrict__ Wl, const float* __restrict__ bl,
             const float* __restrict__ bias, const float* __restrict__ gamma,
             const float* __restrict__ beta,
             float* __restrict__ ws, float* __restrict__ out)
{
  const int CHUNK = (NN + (int)gridDim.x - 1) / (int)gridDim.x;
  int n0 = blockIdx.x * CHUNK;
  if (n0 >= NN) return;
  int n1 = n0 + CHUNK; if (n1 > NN) n1 = NN;
  int d = threadIdx.x & 127;
  int row = threadIdx.x >> 7;
  const float invN = 1.f / (float)NN;
  float mean = ws[WS_BNSUM + d] * invN;
  float var = fmaf(ws[WS_BNSQ + d], invN, -mean * mean);
  float scale = gamma[d] * rsqrtf(var + 1e-5f);
  float shift = fmaf(-mean, scale, beta[d]);
  float wl0 = Wl[d], wl1 = Wl[128 + d];
  float b0 = bl[d], b1 = bl[128 + d];
  float bs = bias[d];
  __shared__ float pool[4][128];
  for (int i = threadIdx.x; i < 512; i += 256) ((float*)pool)[i] = 0.f;
  __syncthreads();
  int g0 = batch[n0];
  for (int n = n0 + row; n < n1; n += 2) {
    float4 a = *(const float4*)&ws[WS_ACC + 4 * n];
    float o = node_out4(a, wl0, wl1, b0, b1, bs);
    float v = fmaf(o, scale, shift);
    v = v > 0.f ? v : 0.01f * v;
    int g = batch[n];
    int slot = g - g0;                    // >= 0: batch is sorted
    if (slot < 4) atomicAdd(&pool[slot][d], v);
    else atomicAdd(&out[g * 128 + d], v); // >4 graphs in chunk: rare fallback
  }
  __syncthreads();
  for (int i = threadIdx.x; i < 512; i += 256) {
    int slot = i >> 7, dd = i & 127;
    int g = g0 + slot;
    float v = pool[slot][dd];
    if (g < NG && v != 0.f) atomicAdd(&out[g * 128 + dd], v);
  }
}

extern "C" void kernel_launch(void* const* d_in, const int* in_sizes, int n_in,
                              void* d_out, int out_size, void* d_ws, size_t ws_size,
                              hipStream_t stream) {
  const float* x     = (const float*)d_in[0];
  const int*   ei    = (const int*)d_in[1];
  const float* eattr = (const float*)d_in[2];
  const int*   batch = (const int*)d_in[3];
  const float* Wl    = (const float*)d_in[4];
  const float* bl    = (const float*)d_in[5];
  const float* Wr    = (const float*)d_in[6];
  const float* br    = (const float*)d_in[7];
  const float* We    = (const float*)d_in[8];
  const float* att   = (const float*)d_in[9];
  const float* bias  = (const float*)d_in[10];
  const float* gam   = (const float*)d_in[11];
  const float* bet   = (const float*)d_in[12];
  float* ws  = (float*)d_ws;
  float* out = (float*)d_out;

  const bool dense = (ws_size >= WS_NEED_BYTES);
  const int EB = (NE / 4 + 255) / 256;   // edge blocks (4 edges/thread)

  hipLaunchKernelGGL(k0_init, dim3(128), dim3(256), 0, stream,
                     ws, att, Wl, Wr, We, bl, br, out, dense ? 1 : 0);
  if (dense) {
    hipLaunchKernelGGL(ke_edge, dim3(EB), dim3(256), 0, stream,
                       ei, x, eattr, Wl, Wr, We, bl, br, att, ws);
    hipLaunchKernelGGL(kf_gather, dim3((NN + 255) / 256), dim3(256), 0, stream, ws);
  } else {
    hipLaunchKernelGGL(k12f, dim3(EB), dim3(256), 0, stream,
                       ei, x, eattr, Wl, Wr, We, bl, br, att, ws);
  }
  hipLaunchKernelGGL(k3_stats, dim3(256), dim3(256), 0, stream,
                     Wl, bl, bias, ws);
  hipLaunchKernelGGL(k4_pool, dim3(256), dim3(256), 0, stream,
                     batch, Wl, bl, bias, gam, bet, ws, out);
}